// Round 2
// baseline (633.862 us; speedup 1.0000x reference)
//
#include <hip/hip_runtime.h>
#include <math.h>

#define EPSF 1e-6f
#define NUM_V 10
#define W_IMG 2000
#define H_IMG 1500
#define HW_IMG (W_IMG * H_IMG)

__device__ __forceinline__ void cross3(const float a[3], const float b[3], float c[3]) {
    c[0] = a[1] * b[2] - a[2] * b[1];
    c[1] = a[2] * b[0] - a[0] * b[2];
    c[2] = a[0] * b[1] - a[1] * b[0];
}
__device__ __forceinline__ float dot3(const float a[3], const float b[3]) {
    return a[0] * b[0] + a[1] * b[1] + a[2] * b[2];
}
__device__ __forceinline__ float norm3(const float a[3]) {
    return sqrtf(a[0] * a[0] + a[1] * a[1] + a[2] * a[2]);
}

// Build T = K2h @ E2 @ inv(E1) and zero accumulators. Called from one thread.
__device__ void do_init(const float* __restrict__ K2, const float* __restrict__ E1,
                        const float* __restrict__ E2, double* __restrict__ acc,
                        unsigned long long* __restrict__ cnt, float* __restrict__ T) {
    acc[0] = 0.0;
    acc[1] = 0.0;
    acc[2] = 0.0;
    *cnt = 0ull;
    double M[4][8];
    for (int i = 0; i < 4; ++i)
        for (int j = 0; j < 4; ++j) {
            M[i][j] = (double)E1[i * 4 + j];
            M[i][j + 4] = (i == j) ? 1.0 : 0.0;
        }
    for (int col = 0; col < 4; ++col) {
        int piv = col;
        double best = fabs(M[col][col]);
        for (int r = col + 1; r < 4; ++r) {
            double v = fabs(M[r][col]);
            if (v > best) { best = v; piv = r; }
        }
        if (piv != col)
            for (int j = 0; j < 8; ++j) {
                double t = M[col][j];
                M[col][j] = M[piv][j];
                M[piv][j] = t;
            }
        double d = M[col][col];
        for (int j = 0; j < 8; ++j) M[col][j] /= d;
        for (int r = 0; r < 4; ++r) {
            if (r == col) continue;
            double f = M[r][col];
            for (int j = 0; j < 8; ++j) M[r][j] -= f * M[col][j];
        }
    }
    double E[4][4];
    for (int i = 0; i < 4; ++i)
        for (int j = 0; j < 4; ++j) {
            double s = 0.0;
            for (int k = 0; k < 4; ++k) s += (double)E2[i * 4 + k] * M[k][j + 4];
            E[i][j] = s;
        }
    for (int i = 0; i < 4; ++i)
        for (int j = 0; j < 4; ++j) {
            double s = 0.0;
            if (i < 3) {
                for (int k = 0; k < 3; ++k) s += (double)K2[i * 3 + k] * E[k][j];
            } else {
                s = E[3][j];
            }
            T[i * 4 + j] = (float)s;
        }
}

// Repack planar (3,H,W) -> interleaved (H,W,4) float4; fold init into thread 0.
__global__ __launch_bounds__(256) void repack_kernel(
    const float* __restrict__ rgb1, const float* __restrict__ rgb2, float4* __restrict__ img1,
    float4* __restrict__ img2, const float* __restrict__ K2, const float* __restrict__ E1,
    const float* __restrict__ E2, double* __restrict__ acc, unsigned long long* __restrict__ cnt,
    float* __restrict__ T) {
    const int idx = blockIdx.x * 256 + threadIdx.x;
    if (idx == 0) do_init(K2, E1, E2, acc, cnt, T);
    if (idx < HW_IMG) {
        img1[idx] = make_float4(rgb1[idx], rgb1[idx + HW_IMG], rgb1[idx + 2 * HW_IMG], 0.f);
    } else if (idx < 2 * HW_IMG) {
        const int p = idx - HW_IMG;
        img2[p] = make_float4(rgb2[p], rgb2[p + HW_IMG], rgb2[p + 2 * HW_IMG], 0.f);
    }
}

// Bilinear tap from (H,W,4) image: one 16B-aligned dwordx4 per tap.
__device__ __forceinline__ float4 sample4(const float4* __restrict__ img, float u, float v) {
    float x = u * (float)(W_IMG - 1);
    float y = v * (float)(H_IMG - 1);
    float fx = floorf(x), fy = floorf(y);
    int x0 = (int)fx, y0 = (int)fy;
    int x1 = min(x0 + 1, W_IMG - 1);
    int y1 = min(y0 + 1, H_IMG - 1);
    float wx = x - fx, wy = y - fy;
    float w00 = (1.f - wx) * (1.f - wy);
    float w01 = wx * (1.f - wy);
    float w10 = (1.f - wx) * wy;
    float w11 = wx * wy;
    float4 a = img[y0 * W_IMG + x0];
    float4 b = img[y0 * W_IMG + x1];
    float4 c = img[y1 * W_IMG + x0];
    float4 d = img[y1 * W_IMG + x1];
    float4 r;
    r.x = fmaf(a.x, w00, fmaf(b.x, w01, fmaf(c.x, w10, d.x * w11)));
    r.y = fmaf(a.y, w00, fmaf(b.y, w01, fmaf(c.y, w10, d.y * w11)));
    r.z = fmaf(a.z, w00, fmaf(b.z, w01, fmaf(c.z, w10, d.z * w11)));
    r.w = 0.f;
    return r;
}

template <bool PACKED>
__global__ __launch_bounds__(256) void edge_kernel(
    const float* __restrict__ ep, const float* __restrict__ K1, const void* __restrict__ im1,
    const void* __restrict__ im2, const float* __restrict__ T, double* __restrict__ acc,
    unsigned long long* __restrict__ cnt) {
    __shared__ float s_geo[11];
    __shared__ int s_nsamp;
    __shared__ float s_wsum[4];

    const int e = blockIdx.x;
    if (threadIdx.x == 0) {
        const float* P = ep + (size_t)e * 12;
        float p0[3] = {P[0], P[1], P[2]};
        float p1[3] = {P[3], P[4], P[5]};
        float p2[3] = {P[6], P[7], P[8]};
        float p3[3] = {P[9], P[10], P[11]};
        float cd[3] = {p1[0] - p0[0], p1[1] - p0[1], p1[2] - p0[2]};
        float nd[3] = {p3[0] - p1[0], p3[1] - p1[1], p3[2] - p1[2]};
        float pd[3] = {p0[0] - p2[0], p0[1] - p2[1], p0[2] - p2[2]};
        float ce[3] = {cd[0] + EPSF, cd[1] + EPSF, cd[2] + EPSF};
        float clen = norm3(ce);
        float dir[3] = {cd[0] / clen, cd[1] / clen, cd[2] / clen};
        float cn[3];
        cross3(dir, nd, cn);
        float n1 = norm3(cn) + EPSF;
        cn[0] /= n1; cn[1] /= n1; cn[2] /= n1;
        if (cn[2] > 0.f) { cn[0] = -cn[0]; cn[1] = -cn[1]; cn[2] = -cn[2]; }
        float up[3];
        cross3(cn, dir, up);
        float n2 = norm3(up) + EPSF;
        up[0] /= n2; up[1] /= n2; up[2] /= n2;
        float pn[3];
        cross3(pd, dir, pn);
        float n3 = norm3(pn) + EPSF;
        pn[0] /= n3; pn[1] /= n3; pn[2] /= n3;
        float obs[3];
        cross3(p0, p1, obs);
        float n4 = norm3(obs) + EPSF;
        obs[0] /= n4; obs[1] /= n4; obs[2] /= n4;
        int nh = (int)floorf(clen / 0.05f);
        nh = max(2, min(1000, nh));
        float nl = 1.f - dot3(cn, pn);
        float snp = fminf(fabsf(dot3(up, obs)), 0.5f);
        float zl = 1.f - snp * 2.f;
        atomicAdd(&acc[1], (double)nl);
        atomicAdd(&acc[2], (double)zl);
        atomicAdd(cnt, (unsigned long long)(nh * NUM_V));
        s_geo[0] = p0[0]; s_geo[1] = p0[1]; s_geo[2] = p0[2];
        s_geo[3] = dir[0]; s_geo[4] = dir[1]; s_geo[5] = dir[2];
        s_geo[6] = up[0]; s_geo[7] = up[1]; s_geo[8] = up[2];
        s_geo[9] = clen;
        s_geo[10] = (float)(nh - 1);
        s_nsamp = nh * NUM_V;
    }
    __syncthreads();

    const float sx = s_geo[0], sy = s_geo[1], sz = s_geo[2];
    const float dx = s_geo[3], dyr = s_geo[4], dz = s_geo[5];
    const float ux = s_geo[6], uy = s_geo[7], uz = s_geo[8];
    const float len = s_geo[9];
    const float denom = s_geo[10];
    const int nsamp = s_nsamp;

    const float k00 = K1[0], k01 = K1[1], k02 = K1[2];
    const float k10 = K1[3], k11 = K1[4], k12 = K1[5];
    const float k20 = K1[6], k21 = K1[7], k22 = K1[8];
    const float t00 = T[0], t01 = T[1], t02 = T[2], t03 = T[3];
    const float t10 = T[4], t11 = T[5], t12 = T[6], t13 = T[7];
    const float t20 = T[8], t21 = T[9], t22 = T[10], t23 = T[11];

    float lsum = 0.f;
    for (int i = threadIdx.x; i < nsamp; i += 256) {
        int px = i / NUM_V;
        int dy = i - px * NUM_V;
        float cx = ((float)px / denom) * len;
        float cy = ((float)dy / 9.0f) * 0.5f;
        float X = fmaf(dx, cx, fmaf(ux, cy, sx));
        float Y = fmaf(dyr, cx, fmaf(uy, cy, sy));
        float Z = fmaf(dz, cx, fmaf(uz, cy, sz));
        float w1 = fmaf(k20, X, fmaf(k21, Y, k22 * Z));
        float u1 = fminf(fmaxf(fmaf(k00, X, fmaf(k01, Y, k02 * Z)) / w1, 0.f), 0.999999f);
        float v1 = fminf(fmaxf(fmaf(k10, X, fmaf(k11, Y, k12 * Z)) / w1, 0.f), 0.999999f);
        float w2 = fmaf(t20, X, fmaf(t21, Y, fmaf(t22, Z, t23)));
        float u2 = fminf(fmaxf(fmaf(t00, X, fmaf(t01, Y, fmaf(t02, Z, t03))) / w2, 0.f), 0.999999f);
        float v2 = fminf(fmaxf(fmaf(t10, X, fmaf(t11, Y, fmaf(t12, Z, t13))) / w2, 0.f), 0.999999f);

        if (PACKED) {
            float4 s1 = sample4((const float4*)im1, u1, v1);
            float4 s2 = sample4((const float4*)im2, u2, v2);
            float d0 = s1.x - s2.x;
            float d1 = s1.y - s2.y;
            float d2 = s1.z - s2.z;
            lsum += d0 * d0 + d1 * d1 + d2 * d2;
        } else {
            const float* r1 = (const float*)im1;
            const float* r2 = (const float*)im2;
            float x = u1 * (float)(W_IMG - 1), y = v1 * (float)(H_IMG - 1);
            float fx = floorf(x), fy = floorf(y);
            int x0 = (int)fx, y0 = (int)fy;
            int x1 = min(x0 + 1, W_IMG - 1), y1 = min(y0 + 1, H_IMG - 1);
            float wx = x - fx, wy = y - fy;
            float s1c[3], s2c[3];
#pragma unroll
            for (int c = 0; c < 3; ++c) {
                const float* b = r1 + c * HW_IMG;
                s1c[c] = b[y0 * W_IMG + x0] * (1.f - wx) * (1.f - wy) +
                         b[y0 * W_IMG + x1] * wx * (1.f - wy) +
                         b[y1 * W_IMG + x0] * (1.f - wx) * wy + b[y1 * W_IMG + x1] * wx * wy;
            }
            x = u2 * (float)(W_IMG - 1); y = v2 * (float)(H_IMG - 1);
            fx = floorf(x); fy = floorf(y);
            x0 = (int)fx; y0 = (int)fy;
            x1 = min(x0 + 1, W_IMG - 1); y1 = min(y0 + 1, H_IMG - 1);
            wx = x - fx; wy = y - fy;
#pragma unroll
            for (int c = 0; c < 3; ++c) {
                const float* b = r2 + c * HW_IMG;
                s2c[c] = b[y0 * W_IMG + x0] * (1.f - wx) * (1.f - wy) +
                         b[y0 * W_IMG + x1] * wx * (1.f - wy) +
                         b[y1 * W_IMG + x0] * (1.f - wx) * wy + b[y1 * W_IMG + x1] * wx * wy;
            }
            float d0 = s1c[0] - s2c[0];
            float d1 = s1c[1] - s2c[1];
            float d2 = s1c[2] - s2c[2];
            lsum += d0 * d0 + d1 * d1 + d2 * d2;
        }
    }

#pragma unroll
    for (int off = 32; off > 0; off >>= 1) lsum += __shfl_down(lsum, off);
    const int wave = threadIdx.x >> 6;
    const int lane = threadIdx.x & 63;
    if (lane == 0) s_wsum[wave] = lsum;
    __syncthreads();
    if (threadIdx.x == 0) {
        float tot = s_wsum[0] + s_wsum[1] + s_wsum[2] + s_wsum[3];
        atomicAdd(&acc[0], (double)tot);
    }
}

__global__ void init_kernel(const float* __restrict__ K2, const float* __restrict__ E1,
                            const float* __restrict__ E2, double* __restrict__ acc,
                            unsigned long long* __restrict__ cnt, float* __restrict__ T) {
    if (threadIdx.x == 0) do_init(K2, E1, E2, acc, cnt, T);
}

__global__ void finalize_kernel(const double* __restrict__ acc,
                                const unsigned long long* __restrict__ cnt,
                                float* __restrict__ out, int N) {
    if (threadIdx.x == 0) {
        double c = (double)(*cnt) * 3.0;
        out[0] = (float)(acc[0] / c);
        out[1] = (float)(acc[1] / (double)N * 0.5);
        out[2] = (float)(acc[2] / (double)N);
    }
}

extern "C" void kernel_launch(void* const* d_in, const int* in_sizes, int n_in, void* d_out,
                              int out_size, void* d_ws, size_t ws_size, hipStream_t stream) {
    const float* ep = (const float*)d_in[0];
    const float* K1 = (const float*)d_in[1];
    const float* K2 = (const float*)d_in[2];
    const float* E1 = (const float*)d_in[3];
    const float* E2 = (const float*)d_in[4];
    const float* rgb1 = (const float*)d_in[5];
    const float* rgb2 = (const float*)d_in[6];
    float* out = (float*)d_out;
    const int N = in_sizes[0] / 12;

    double* acc = (double*)d_ws;                 // 3 doubles
    unsigned long long* cnt = (unsigned long long*)(acc + 3);
    float* T = (float*)(acc + 4);                // 16 floats
    // 256B-aligned image region after the header
    char* img_base = (char*)d_ws + 256;
    float4* img1 = (float4*)img_base;
    float4* img2 = img1 + HW_IMG;
    const size_t need = 256 + 2 * (size_t)HW_IMG * sizeof(float4);

    if (ws_size >= need) {
        const int total = 2 * HW_IMG;
        repack_kernel<<<(total + 255) / 256, 256, 0, stream>>>(rgb1, rgb2, img1, img2, K2, E1,
                                                               E2, acc, cnt, T);
        edge_kernel<true><<<N, 256, 0, stream>>>(ep, K1, img1, img2, T, acc, cnt);
    } else {
        init_kernel<<<1, 64, 0, stream>>>(K2, E1, E2, acc, cnt, T);
        edge_kernel<false><<<N, 256, 0, stream>>>(ep, K1, rgb1, rgb2, T, acc, cnt);
    }
    finalize_kernel<<<1, 64, 0, stream>>>(acc, cnt, out, N);
}

// Round 3
// 249.644 us; speedup vs baseline: 2.5391x; 2.5391x over previous
//
#include <hip/hip_runtime.h>
#include <math.h>

#define EPSF 1e-6f
#define NUM_V 10
#define W_IMG 2000
#define H_IMG 1500
#define HW_IMG (W_IMG * H_IMG)

__device__ __forceinline__ void cross3(const float a[3], const float b[3], float c[3]) {
    c[0] = a[1] * b[2] - a[2] * b[1];
    c[1] = a[2] * b[0] - a[0] * b[2];
    c[2] = a[0] * b[1] - a[1] * b[0];
}
__device__ __forceinline__ float dot3(const float a[3], const float b[3]) {
    return a[0] * b[0] + a[1] * b[1] + a[2] * b[2];
}
__device__ __forceinline__ float norm3(const float a[3]) {
    return sqrtf(a[0] * a[0] + a[1] * a[1] + a[2] * a[2]);
}

// ---- init: T = K2h @ E2 @ inv(E1) (one thread; no shared accumulators anymore) ----
__global__ void init_kernel(const float* __restrict__ K2, const float* __restrict__ E1,
                            const float* __restrict__ E2, float* __restrict__ T) {
    if (threadIdx.x != 0) return;
    double M[4][8];
    for (int i = 0; i < 4; ++i)
        for (int j = 0; j < 4; ++j) {
            M[i][j] = (double)E1[i * 4 + j];
            M[i][j + 4] = (i == j) ? 1.0 : 0.0;
        }
    for (int col = 0; col < 4; ++col) {
        int piv = col;
        double best = fabs(M[col][col]);
        for (int r = col + 1; r < 4; ++r) {
            double v = fabs(M[r][col]);
            if (v > best) { best = v; piv = r; }
        }
        if (piv != col)
            for (int j = 0; j < 8; ++j) {
                double t = M[col][j]; M[col][j] = M[piv][j]; M[piv][j] = t;
            }
        double d = M[col][col];
        for (int j = 0; j < 8; ++j) M[col][j] /= d;
        for (int r = 0; r < 4; ++r) {
            if (r == col) continue;
            double f = M[r][col];
            for (int j = 0; j < 8; ++j) M[r][j] -= f * M[col][j];
        }
    }
    double E[4][4];
    for (int i = 0; i < 4; ++i)
        for (int j = 0; j < 4; ++j) {
            double s = 0.0;
            for (int k = 0; k < 4; ++k) s += (double)E2[i * 4 + k] * M[k][j + 4];
            E[i][j] = s;
        }
    for (int i = 0; i < 4; ++i)
        for (int j = 0; j < 4; ++j) {
            double s = 0.0;
            if (i < 3) {
                for (int k = 0; k < 3; ++k) s += (double)K2[i * 3 + k] * E[k][j];
            } else {
                s = E[3][j];
            }
            T[i * 4 + j] = (float)s;
        }
}

// ---- geom: one thread per edge; per-wave loss partials to distinct slots (atomic-free) ----
__global__ __launch_bounds__(256) void geom_kernel(const float* __restrict__ ep, int N,
                                                   float4* __restrict__ geo,
                                                   double* __restrict__ gnl,
                                                   double* __restrict__ gzl,
                                                   double* __restrict__ gcnt) {
    const int e = blockIdx.x * 256 + threadIdx.x;
    float nl = 0.f, zl = 0.f;
    int cn = 0;
    if (e < N) {
        const float4* P4 = (const float4*)(ep + (size_t)e * 12);
        float4 a4 = P4[0], b4 = P4[1], c4 = P4[2];
        float p0[3] = {a4.x, a4.y, a4.z};
        float p1[3] = {a4.w, b4.x, b4.y};
        float p2[3] = {b4.z, b4.w, c4.x};
        float p3[3] = {c4.y, c4.z, c4.w};
        float cd[3] = {p1[0] - p0[0], p1[1] - p0[1], p1[2] - p0[2]};
        float nd[3] = {p3[0] - p1[0], p3[1] - p1[1], p3[2] - p1[2]};
        float pd[3] = {p0[0] - p2[0], p0[1] - p2[1], p0[2] - p2[2]};
        float ce[3] = {cd[0] + EPSF, cd[1] + EPSF, cd[2] + EPSF};
        float clen = norm3(ce);
        float dir[3] = {cd[0] / clen, cd[1] / clen, cd[2] / clen};
        float cnv[3];
        cross3(dir, nd, cnv);
        float n1 = norm3(cnv) + EPSF;
        cnv[0] /= n1; cnv[1] /= n1; cnv[2] /= n1;
        if (cnv[2] > 0.f) { cnv[0] = -cnv[0]; cnv[1] = -cnv[1]; cnv[2] = -cnv[2]; }
        float up[3];
        cross3(cnv, dir, up);
        float n2 = norm3(up) + EPSF;
        up[0] /= n2; up[1] /= n2; up[2] /= n2;
        float pn[3];
        cross3(pd, dir, pn);
        float n3 = norm3(pn) + EPSF;
        pn[0] /= n3; pn[1] /= n3; pn[2] /= n3;
        float obs[3];
        cross3(p0, p1, obs);
        float n4 = norm3(obs) + EPSF;
        obs[0] /= n4; obs[1] /= n4; obs[2] /= n4;
        int nh = (int)floorf(clen / 0.05f);
        nh = max(2, min(1000, nh));
        nl = 1.f - dot3(cnv, pn);
        float snp = fminf(fabsf(dot3(up, obs)), 0.5f);
        zl = 1.f - snp * 2.f;
        cn = nh * NUM_V;
        geo[3 * e + 0] = make_float4(p0[0], p0[1], p0[2], clen);
        geo[3 * e + 1] = make_float4(dir[0], dir[1], dir[2], (float)(nh - 1));
        geo[3 * e + 2] = make_float4(up[0], up[1], up[2], __int_as_float(cn));
    }
#pragma unroll
    for (int off = 32; off > 0; off >>= 1) {
        nl += __shfl_down(nl, off);
        zl += __shfl_down(zl, off);
        cn += __shfl_down(cn, off);
    }
    if ((threadIdx.x & 63) == 0) {
        const int w = blockIdx.x * 4 + (threadIdx.x >> 6);
        gnl[w] = (double)nl;
        gzl[w] = (double)zl;
        gcnt[w] = (double)cn;
    }
}

// ---- repack planar (3,H,W) -> (H,W,4) float4, 4 pixels/thread ----
__global__ __launch_bounds__(256) void repack_kernel(const float* __restrict__ rgb1,
                                                     const float* __restrict__ rgb2,
                                                     float4* __restrict__ img1,
                                                     float4* __restrict__ img2) {
    const int t = blockIdx.x * 256 + threadIdx.x;
    const int p = t * 4;  // pixel index within one image (both images concatenated)
    const float* src;
    float4* dst;
    int q;
    if (p < HW_IMG) {
        src = rgb1; dst = img1; q = p;
    } else if (p < 2 * HW_IMG) {
        src = rgb2; dst = img2; q = p - HW_IMG;
    } else {
        return;
    }
    float4 r = *(const float4*)(src + q);
    float4 g = *(const float4*)(src + q + HW_IMG);
    float4 b = *(const float4*)(src + q + 2 * HW_IMG);
    dst[q + 0] = make_float4(r.x, g.x, b.x, 0.f);
    dst[q + 1] = make_float4(r.y, g.y, b.y, 0.f);
    dst[q + 2] = make_float4(r.z, g.z, b.z, 0.f);
    dst[q + 3] = make_float4(r.w, g.w, b.w, 0.f);
}

__device__ __forceinline__ float4 sample4(const float4* __restrict__ img, float u, float v) {
    float x = u * (float)(W_IMG - 1);
    float y = v * (float)(H_IMG - 1);
    float fx = floorf(x), fy = floorf(y);
    int x0 = (int)fx, y0 = (int)fy;
    int x1 = min(x0 + 1, W_IMG - 1);
    int y1 = min(y0 + 1, H_IMG - 1);
    float wx = x - fx, wy = y - fy;
    float w00 = (1.f - wx) * (1.f - wy);
    float w01 = wx * (1.f - wy);
    float w10 = (1.f - wx) * wy;
    float w11 = wx * wy;
    float4 a = img[y0 * W_IMG + x0];
    float4 b = img[y0 * W_IMG + x1];
    float4 c = img[y1 * W_IMG + x0];
    float4 d = img[y1 * W_IMG + x1];
    float4 r;
    r.x = fmaf(a.x, w00, fmaf(b.x, w01, fmaf(c.x, w10, d.x * w11)));
    r.y = fmaf(a.y, w00, fmaf(b.y, w01, fmaf(c.y, w10, d.y * w11)));
    r.z = fmaf(a.z, w00, fmaf(b.z, w01, fmaf(c.z, w10, d.z * w11)));
    r.w = 0.f;
    return r;
}

// ---- sample: one WAVE per edge; atomic-free per-edge partial ----
__global__ __launch_bounds__(256) void sample_kernel(const float4* __restrict__ geo,
                                                     const float* __restrict__ K1,
                                                     const float* __restrict__ T,
                                                     const float4* __restrict__ img1,
                                                     const float4* __restrict__ img2,
                                                     double* __restrict__ part, int N) {
    const int w = blockIdx.x * 4 + (threadIdx.x >> 6);
    if (w >= N) return;
    const int lane = threadIdx.x & 63;

    const float4 g0 = geo[3 * w + 0];
    const float4 g1 = geo[3 * w + 1];
    const float4 g2 = geo[3 * w + 2];
    const float sx = g0.x, sy = g0.y, sz = g0.z, len = g0.w;
    const float dx = g1.x, dyc = g1.y, dz = g1.z, denom = g1.w;
    const float ux = g2.x, uy = g2.y, uz = g2.z;
    const int nsamp = __float_as_int(g2.w);

    const float k00 = K1[0], k01 = K1[1], k02 = K1[2];
    const float k10 = K1[3], k11 = K1[4], k12 = K1[5];
    const float k20 = K1[6], k21 = K1[7], k22 = K1[8];
    const float t00 = T[0], t01 = T[1], t02 = T[2], t03 = T[3];
    const float t10 = T[4], t11 = T[5], t12 = T[6], t13 = T[7];
    const float t20 = T[8], t21 = T[9], t22 = T[10], t23 = T[11];

    float lsum = 0.f;

    auto body = [&](int i) {
        int px = i / NUM_V;
        int dy = i - px * NUM_V;
        float cx = ((float)px / denom) * len;
        float cy = ((float)dy / 9.0f) * 0.5f;
        float X = fmaf(dx, cx, fmaf(ux, cy, sx));
        float Y = fmaf(dyc, cx, fmaf(uy, cy, sy));
        float Z = fmaf(dz, cx, fmaf(uz, cy, sz));
        float w1 = fmaf(k20, X, fmaf(k21, Y, k22 * Z));
        float u1 = fminf(fmaxf(fmaf(k00, X, fmaf(k01, Y, k02 * Z)) / w1, 0.f), 0.999999f);
        float v1 = fminf(fmaxf(fmaf(k10, X, fmaf(k11, Y, k12 * Z)) / w1, 0.f), 0.999999f);
        float w2 = fmaf(t20, X, fmaf(t21, Y, fmaf(t22, Z, t23)));
        float u2 = fminf(fmaxf(fmaf(t00, X, fmaf(t01, Y, fmaf(t02, Z, t03))) / w2, 0.f), 0.999999f);
        float v2 = fminf(fmaxf(fmaf(t10, X, fmaf(t11, Y, fmaf(t12, Z, t13))) / w2, 0.f), 0.999999f);
        float4 s1 = sample4(img1, u1, v1);
        float4 s2 = sample4(img2, u2, v2);
        float d0 = s1.x - s2.x;
        float d1 = s1.y - s2.y;
        float d2 = s1.z - s2.z;
        return d0 * d0 + d1 * d1 + d2 * d2;
    };

    int i = lane;
    for (; i + 64 < nsamp; i += 128) {
        // two independent samples in flight (16 gathers) per unrolled iteration
        float a = body(i);
        float b = body(i + 64);
        lsum += a + b;
    }
    if (i < nsamp) lsum += body(i);

#pragma unroll
    for (int off = 32; off > 0; off >>= 1) lsum += __shfl_down(lsum, off);
    if (lane == 0) part[w] = (double)lsum;
}

// ---- finalize: single block reduces all partials ----
__global__ __launch_bounds__(256) void finalize_kernel(const double* __restrict__ part,
                                                       const double* __restrict__ gnl,
                                                       const double* __restrict__ gzl,
                                                       const double* __restrict__ gcnt, int N,
                                                       int NW, float* __restrict__ out) {
    __shared__ double s_s[4], s_a[4], s_b[4], s_c[4];
    double s = 0.0, a = 0.0, b = 0.0, c = 0.0;
    for (int i = threadIdx.x; i < N; i += 256) s += part[i];
    for (int i = threadIdx.x; i < NW; i += 256) {
        a += gnl[i];
        b += gzl[i];
        c += gcnt[i];
    }
#pragma unroll
    for (int off = 32; off > 0; off >>= 1) {
        s += __shfl_down(s, off);
        a += __shfl_down(a, off);
        b += __shfl_down(b, off);
        c += __shfl_down(c, off);
    }
    const int wave = threadIdx.x >> 6;
    if ((threadIdx.x & 63) == 0) {
        s_s[wave] = s; s_a[wave] = a; s_b[wave] = b; s_c[wave] = c;
    }
    __syncthreads();
    if (threadIdx.x == 0) {
        double S = s_s[0] + s_s[1] + s_s[2] + s_s[3];
        double A = s_a[0] + s_a[1] + s_a[2] + s_a[3];
        double B = s_b[0] + s_b[1] + s_b[2] + s_b[3];
        double C = s_c[0] + s_c[1] + s_c[2] + s_c[3];
        out[0] = (float)(S / (C * 3.0));
        out[1] = (float)(A / (double)N * 0.5);
        out[2] = (float)(B / (double)N);
    }
}

extern "C" void kernel_launch(void* const* d_in, const int* in_sizes, int n_in, void* d_out,
                              int out_size, void* d_ws, size_t ws_size, hipStream_t stream) {
    const float* ep = (const float*)d_in[0];
    const float* K1 = (const float*)d_in[1];
    const float* K2 = (const float*)d_in[2];
    const float* E1 = (const float*)d_in[3];
    const float* E2 = (const float*)d_in[4];
    const float* rgb1 = (const float*)d_in[5];
    const float* rgb2 = (const float*)d_in[6];
    float* out = (float*)d_out;
    const int N = in_sizes[0] / 12;

    const int GB = (N + 255) / 256;  // geom blocks
    const int NW = GB * 4;           // geom wave-partial slots

    // ws layout (all 256B-aligned regions):
    char* p = (char*)d_ws;
    float* T = (float*)p;                       p += 256;
    float4* geo = (float4*)p;                   p += (size_t)3 * N * sizeof(float4);
    p = (char*)(((size_t)p + 255) & ~(size_t)255);
    double* part = (double*)p;                  p += (size_t)N * sizeof(double);
    double* gnl = (double*)p;                   p += (size_t)NW * sizeof(double);
    double* gzl = (double*)p;                   p += (size_t)NW * sizeof(double);
    double* gcnt = (double*)p;                  p += (size_t)NW * sizeof(double);
    p = (char*)(((size_t)p + 255) & ~(size_t)255);
    float4* img1 = (float4*)p;
    float4* img2 = img1 + HW_IMG;

    init_kernel<<<1, 64, 0, stream>>>(K2, E1, E2, T);
    geom_kernel<<<GB, 256, 0, stream>>>(ep, N, geo, gnl, gzl, gcnt);
    const int rp_threads = (2 * HW_IMG) / 4;
    repack_kernel<<<(rp_threads + 255) / 256, 256, 0, stream>>>(rgb1, rgb2, img1, img2);
    sample_kernel<<<(N + 3) / 4, 256, 0, stream>>>(geo, K1, T, img1, img2, part, N);
    finalize_kernel<<<1, 256, 0, stream>>>(part, gnl, gzl, gcnt, N, NW, out);
}

// Round 4
// 202.586 us; speedup vs baseline: 3.1288x; 1.2323x over previous
//
#include <hip/hip_runtime.h>
#include <hip/hip_fp16.h>
#include <math.h>

#define EPSF 1e-6f
#define NUM_V 10
#define W_IMG 2000
#define H_IMG 1500
#define HW_IMG (W_IMG * H_IMG)
#define SAMPLE_BLOCKS 2048            // 8192 waves = 256 CU x 32 waves
#define MAX_WAVES_PER_EDGE 160        // ceil(1000*10/64)=157, margin

__device__ __forceinline__ void cross3(const float a[3], const float b[3], float c[3]) {
    c[0] = a[1] * b[2] - a[2] * b[1];
    c[1] = a[2] * b[0] - a[0] * b[2];
    c[2] = a[0] * b[1] - a[1] * b[0];
}
__device__ __forceinline__ float dot3(const float a[3], const float b[3]) {
    return a[0] * b[0] + a[1] * b[1] + a[2] * b[2];
}
__device__ __forceinline__ float norm3(const float a[3]) {
    return sqrtf(a[0] * a[0] + a[1] * a[1] + a[2] * a[2]);
}
__device__ __forceinline__ unsigned pack2(float a, float b) {
    unsigned short ua = __half_as_ushort(__float2half_rn(a));
    unsigned short ub = __half_as_ushort(__float2half_rn(b));
    return (unsigned)ua | ((unsigned)ub << 16);
}
__device__ __forceinline__ float hlo(unsigned u) {
    return __half2float(__ushort_as_half((unsigned short)(u & 0xffffu)));
}
__device__ __forceinline__ float hhi(unsigned u) {
    return __half2float(__ushort_as_half((unsigned short)(u >> 16)));
}

// ---- T = K2h @ E2 @ inv(E1), one thread ----
__device__ void do_init(const float* __restrict__ K2, const float* __restrict__ E1,
                        const float* __restrict__ E2, float* __restrict__ T) {
    double M[4][8];
    for (int i = 0; i < 4; ++i)
        for (int j = 0; j < 4; ++j) {
            M[i][j] = (double)E1[i * 4 + j];
            M[i][j + 4] = (i == j) ? 1.0 : 0.0;
        }
    for (int col = 0; col < 4; ++col) {
        int piv = col;
        double best = fabs(M[col][col]);
        for (int r = col + 1; r < 4; ++r) {
            double v = fabs(M[r][col]);
            if (v > best) { best = v; piv = r; }
        }
        if (piv != col)
            for (int j = 0; j < 8; ++j) {
                double t = M[col][j]; M[col][j] = M[piv][j]; M[piv][j] = t;
            }
        double d = M[col][col];
        for (int j = 0; j < 8; ++j) M[col][j] /= d;
        for (int r = 0; r < 4; ++r) {
            if (r == col) continue;
            double f = M[r][col];
            for (int j = 0; j < 8; ++j) M[r][j] -= f * M[col][j];
        }
    }
    double E[4][4];
    for (int i = 0; i < 4; ++i)
        for (int j = 0; j < 4; ++j) {
            double s = 0.0;
            for (int k = 0; k < 4; ++k) s += (double)E2[i * 4 + k] * M[k][j + 4];
            E[i][j] = s;
        }
    for (int i = 0; i < 4; ++i)
        for (int j = 0; j < 4; ++j) {
            double s = 0.0;
            if (i < 3) {
                for (int k = 0; k < 3; ++k) s += (double)K2[i * 3 + k] * E[k][j];
            } else {
                s = E[3][j];
            }
            T[i * 4 + j] = (float)s;
        }
}

// ---- geom: thread per edge; also emits per-edge wave count; wave-partial losses ----
__global__ __launch_bounds__(256) void geom_kernel(const float* __restrict__ ep, int N,
                                                   float4* __restrict__ geo,
                                                   int* __restrict__ nwv,
                                                   double* __restrict__ gnl,
                                                   double* __restrict__ gzl,
                                                   double* __restrict__ gcnt) {
    const int e = blockIdx.x * 256 + threadIdx.x;
    float nl = 0.f, zl = 0.f;
    int cn = 0;
    if (e < N) {
        const float4* P4 = (const float4*)(ep + (size_t)e * 12);
        float4 a4 = P4[0], b4 = P4[1], c4 = P4[2];
        float p0[3] = {a4.x, a4.y, a4.z};
        float p1[3] = {a4.w, b4.x, b4.y};
        float p2[3] = {b4.z, b4.w, c4.x};
        float p3[3] = {c4.y, c4.z, c4.w};
        float cd[3] = {p1[0] - p0[0], p1[1] - p0[1], p1[2] - p0[2]};
        float nd[3] = {p3[0] - p1[0], p3[1] - p1[1], p3[2] - p1[2]};
        float pd[3] = {p0[0] - p2[0], p0[1] - p2[1], p0[2] - p2[2]};
        float ce[3] = {cd[0] + EPSF, cd[1] + EPSF, cd[2] + EPSF};
        float clen = norm3(ce);
        float dir[3] = {cd[0] / clen, cd[1] / clen, cd[2] / clen};
        float cnv[3];
        cross3(dir, nd, cnv);
        float n1 = norm3(cnv) + EPSF;
        cnv[0] /= n1; cnv[1] /= n1; cnv[2] /= n1;
        if (cnv[2] > 0.f) { cnv[0] = -cnv[0]; cnv[1] = -cnv[1]; cnv[2] = -cnv[2]; }
        float up[3];
        cross3(cnv, dir, up);
        float n2 = norm3(up) + EPSF;
        up[0] /= n2; up[1] /= n2; up[2] /= n2;
        float pn[3];
        cross3(pd, dir, pn);
        float n3 = norm3(pn) + EPSF;
        pn[0] /= n3; pn[1] /= n3; pn[2] /= n3;
        float obs[3];
        cross3(p0, p1, obs);
        float n4 = norm3(obs) + EPSF;
        obs[0] /= n4; obs[1] /= n4; obs[2] /= n4;
        int nh = (int)floorf(clen / 0.05f);
        nh = max(2, min(1000, nh));
        nl = 1.f - dot3(cnv, pn);
        float snp = fminf(fabsf(dot3(up, obs)), 0.5f);
        zl = 1.f - snp * 2.f;
        int nsamp = nh * NUM_V;
        cn = nsamp;
        geo[3 * e + 0] = make_float4(p0[0], p0[1], p0[2], clen);
        geo[3 * e + 1] = make_float4(dir[0], dir[1], dir[2], (float)(nh - 1));
        geo[3 * e + 2] = make_float4(up[0], up[1], up[2], __int_as_float(nsamp));
        nwv[e] = (nsamp + 63) / 64;
    }
#pragma unroll
    for (int off = 32; off > 0; off >>= 1) {
        nl += __shfl_down(nl, off);
        zl += __shfl_down(zl, off);
        cn += __shfl_down(cn, off);
    }
    if ((threadIdx.x & 63) == 0) {
        const int w = blockIdx.x * 4 + (threadIdx.x >> 6);
        gnl[w] = (double)nl;
        gzl[w] = (double)zl;
        gcnt[w] = (double)cn;
    }
}

// ---- scan: single block; exclusive prefix of nwv; total; init T on thread 0 ----
__global__ __launch_bounds__(256) void scan_kernel(const int* __restrict__ nwv, int N,
                                                   int* __restrict__ prefix,
                                                   int* __restrict__ total,
                                                   const float* __restrict__ K2,
                                                   const float* __restrict__ E1,
                                                   const float* __restrict__ E2,
                                                   float* __restrict__ T) {
    __shared__ int s_sum[256];
    const int tid = threadIdx.x;
    if (tid == 0) do_init(K2, E1, E2, T);
    const int chunk = (N + 255) / 256;
    const int lo = tid * chunk;
    const int hi = min(lo + chunk, N);
    int s = 0;
    for (int i = lo; i < hi; ++i) s += nwv[i];
    s_sum[tid] = s;
    __syncthreads();
    for (int off = 1; off < 256; off <<= 1) {
        int v = (tid >= off) ? s_sum[tid - off] : 0;
        __syncthreads();
        s_sum[tid] += v;
        __syncthreads();
    }
    int run = s_sum[tid] - s;  // exclusive base
    for (int i = lo; i < hi; ++i) {
        prefix[i] = run;
        run += nwv[i];
    }
    if (tid == 255) {
        prefix[N] = run;
        *total = run;
    }
}

// ---- sched: thread per edge scatters its wave descriptors ----
__global__ __launch_bounds__(256) void sched_kernel(const int* __restrict__ nwv,
                                                    const int* __restrict__ prefix, int N,
                                                    unsigned* __restrict__ sched) {
    const int e = blockIdx.x * 256 + threadIdx.x;
    if (e >= N) return;
    const int base = prefix[e];
    const int k = nwv[e];
    const unsigned tag = ((unsigned)e) << 8;
    for (int j = 0; j < k; ++j) sched[base + j] = tag | (unsigned)j;
}

// ---- repack planar fp32 (3,H,W) -> interleaved half4 (H,W); 2 px/thread ----
__global__ __launch_bounds__(256) void repack_kernel(const float* __restrict__ rgb1,
                                                     const float* __restrict__ rgb2,
                                                     uint2* __restrict__ img1,
                                                     uint2* __restrict__ img2) {
    const int t = blockIdx.x * 256 + threadIdx.x;
    const int p = t * 2;
    const float* src;
    uint2* dst;
    int q;
    if (p < HW_IMG) {
        src = rgb1; dst = img1; q = p;
    } else if (p < 2 * HW_IMG) {
        src = rgb2; dst = img2; q = p - HW_IMG;
    } else {
        return;
    }
    float2 r = *(const float2*)(src + q);
    float2 g = *(const float2*)(src + q + HW_IMG);
    float2 b = *(const float2*)(src + q + 2 * HW_IMG);
    uint4 o;
    o.x = pack2(r.x, g.x);
    o.y = pack2(b.x, 0.f);
    o.z = pack2(r.y, g.y);
    o.w = pack2(b.y, 0.f);
    *(uint4*)(dst + q) = o;
}

__device__ __forceinline__ void sampleH(const uint2* __restrict__ img, float u, float v,
                                        float out[3]) {
    float x = u * (float)(W_IMG - 1);
    float y = v * (float)(H_IMG - 1);
    float fx = floorf(x), fy = floorf(y);
    int x0 = (int)fx, y0 = (int)fy;
    int x1 = min(x0 + 1, W_IMG - 1);
    int y1 = min(y0 + 1, H_IMG - 1);
    float wx = x - fx, wy = y - fy;
    float w00 = (1.f - wx) * (1.f - wy);
    float w01 = wx * (1.f - wy);
    float w10 = (1.f - wx) * wy;
    float w11 = wx * wy;
    uint2 A = img[y0 * W_IMG + x0];
    uint2 B = img[y0 * W_IMG + x1];
    uint2 C = img[y1 * W_IMG + x0];
    uint2 D = img[y1 * W_IMG + x1];
    out[0] = fmaf(hlo(A.x), w00, fmaf(hlo(B.x), w01, fmaf(hlo(C.x), w10, hlo(D.x) * w11)));
    out[1] = fmaf(hhi(A.x), w00, fmaf(hhi(B.x), w01, fmaf(hhi(C.x), w10, hhi(D.x) * w11)));
    out[2] = fmaf(hlo(A.y), w00, fmaf(hlo(B.y), w01, fmaf(hlo(C.y), w10, hlo(D.y) * w11)));
}

// ---- sample: 8192 persistent waves stride the flattened wave-iteration list ----
__global__ __launch_bounds__(256) void sample_kernel(
    const float4* __restrict__ geo, const float* __restrict__ K1, const float* __restrict__ T,
    const uint2* __restrict__ img1, const uint2* __restrict__ img2,
    const unsigned* __restrict__ sched, const int* __restrict__ total_p,
    double* __restrict__ part) {
    const int wid = blockIdx.x * 4 + (threadIdx.x >> 6);
    const int lane = threadIdx.x & 63;
    const int nw = gridDim.x * 4;
    const int total = *total_p;

    const float k00 = K1[0], k01 = K1[1], k02 = K1[2];
    const float k10 = K1[3], k11 = K1[4], k12 = K1[5];
    const float k20 = K1[6], k21 = K1[7], k22 = K1[8];
    const float t00 = T[0], t01 = T[1], t02 = T[2], t03 = T[3];
    const float t10 = T[4], t11 = T[5], t12 = T[6], t13 = T[7];
    const float t20 = T[8], t21 = T[9], t22 = T[10], t23 = T[11];

    double dsum = 0.0;
    for (int idx = wid; idx < total; idx += nw) {
        const unsigned s = (unsigned)__builtin_amdgcn_readfirstlane((int)sched[idx]);
        const int e = (int)(s >> 8);
        const int k = (int)(s & 255u);
        const float4 g0 = geo[3 * e + 0];
        const float4 g1 = geo[3 * e + 1];
        const float4 g2 = geo[3 * e + 2];
        const int nsamp = __float_as_int(g2.w);
        const int i = k * 64 + lane;
        float val = 0.f;
        if (i < nsamp) {
            int px = i / NUM_V;
            int dy = i - px * NUM_V;
            float cx = ((float)px / g1.w) * g0.w;
            float cy = ((float)dy / 9.0f) * 0.5f;
            float X = fmaf(g1.x, cx, fmaf(g2.x, cy, g0.x));
            float Y = fmaf(g1.y, cx, fmaf(g2.y, cy, g0.y));
            float Z = fmaf(g1.z, cx, fmaf(g2.z, cy, g0.z));
            float w1 = fmaf(k20, X, fmaf(k21, Y, k22 * Z));
            float u1 = fminf(fmaxf(fmaf(k00, X, fmaf(k01, Y, k02 * Z)) / w1, 0.f), 0.999999f);
            float v1 = fminf(fmaxf(fmaf(k10, X, fmaf(k11, Y, k12 * Z)) / w1, 0.f), 0.999999f);
            float w2 = fmaf(t20, X, fmaf(t21, Y, fmaf(t22, Z, t23)));
            float u2 =
                fminf(fmaxf(fmaf(t00, X, fmaf(t01, Y, fmaf(t02, Z, t03))) / w2, 0.f), 0.999999f);
            float v2 =
                fminf(fmaxf(fmaf(t10, X, fmaf(t11, Y, fmaf(t12, Z, t13))) / w2, 0.f), 0.999999f);
            float s1[3], s2[3];
            sampleH(img1, u1, v1, s1);
            sampleH(img2, u2, v2, s2);
            float d0 = s1[0] - s2[0];
            float d1 = s1[1] - s2[1];
            float d2 = s1[2] - s2[2];
            val = d0 * d0 + d1 * d1 + d2 * d2;
        }
        dsum += (double)val;
    }
#pragma unroll
    for (int off = 32; off > 0; off >>= 1) dsum += __shfl_down(dsum, off);
    if (lane == 0) part[wid] = dsum;
}

// ---- finalize ----
__global__ __launch_bounds__(256) void finalize_kernel(const double* __restrict__ part, int NP,
                                                       const double* __restrict__ gnl,
                                                       const double* __restrict__ gzl,
                                                       const double* __restrict__ gcnt, int N,
                                                       int NW, float* __restrict__ out) {
    __shared__ double s_s[4], s_a[4], s_b[4], s_c[4];
    double s = 0.0, a = 0.0, b = 0.0, c = 0.0;
    for (int i = threadIdx.x; i < NP; i += 256) s += part[i];
    for (int i = threadIdx.x; i < NW; i += 256) {
        a += gnl[i];
        b += gzl[i];
        c += gcnt[i];
    }
#pragma unroll
    for (int off = 32; off > 0; off >>= 1) {
        s += __shfl_down(s, off);
        a += __shfl_down(a, off);
        b += __shfl_down(b, off);
        c += __shfl_down(c, off);
    }
    const int wave = threadIdx.x >> 6;
    if ((threadIdx.x & 63) == 0) {
        s_s[wave] = s; s_a[wave] = a; s_b[wave] = b; s_c[wave] = c;
    }
    __syncthreads();
    if (threadIdx.x == 0) {
        double S = s_s[0] + s_s[1] + s_s[2] + s_s[3];
        double A = s_a[0] + s_a[1] + s_a[2] + s_a[3];
        double B = s_b[0] + s_b[1] + s_b[2] + s_b[3];
        double C = s_c[0] + s_c[1] + s_c[2] + s_c[3];
        out[0] = (float)(S / (C * 3.0));
        out[1] = (float)(A / (double)N * 0.5);
        out[2] = (float)(B / (double)N);
    }
}

extern "C" void kernel_launch(void* const* d_in, const int* in_sizes, int n_in, void* d_out,
                              int out_size, void* d_ws, size_t ws_size, hipStream_t stream) {
    const float* ep = (const float*)d_in[0];
    const float* K1 = (const float*)d_in[1];
    const float* K2 = (const float*)d_in[2];
    const float* E1 = (const float*)d_in[3];
    const float* E2 = (const float*)d_in[4];
    const float* rgb1 = (const float*)d_in[5];
    const float* rgb2 = (const float*)d_in[6];
    float* out = (float*)d_out;
    const int N = in_sizes[0] / 12;

    const int GB = (N + 255) / 256;
    const int NW = GB * 4;
    const int NPART = SAMPLE_BLOCKS * 4;

    char* p = (char*)d_ws;
    auto align256 = [](char* q) { return (char*)(((size_t)q + 255) & ~(size_t)255); };
    float* T = (float*)p;                 p += 256;
    int* total = (int*)p;                 p += 256;
    float4* geo = (float4*)p;             p += (size_t)3 * N * sizeof(float4);
    p = align256(p);
    int* nwv = (int*)p;                   p += (size_t)N * sizeof(int);
    p = align256(p);
    int* prefix = (int*)p;                p += (size_t)(N + 1) * sizeof(int);
    p = align256(p);
    double* part = (double*)p;            p += (size_t)NPART * sizeof(double);
    double* gnl = (double*)p;             p += (size_t)NW * sizeof(double);
    double* gzl = (double*)p;             p += (size_t)NW * sizeof(double);
    double* gcnt = (double*)p;            p += (size_t)NW * sizeof(double);
    p = align256(p);
    unsigned* sched = (unsigned*)p;       p += (size_t)N * MAX_WAVES_PER_EDGE * sizeof(unsigned);
    p = align256(p);
    uint2* img1 = (uint2*)p;
    uint2* img2 = img1 + HW_IMG;

    repack_kernel<<<(2 * HW_IMG / 2 + 255) / 256, 256, 0, stream>>>(rgb1, rgb2, img1, img2);
    geom_kernel<<<GB, 256, 0, stream>>>(ep, N, geo, nwv, gnl, gzl, gcnt);
    scan_kernel<<<1, 256, 0, stream>>>(nwv, N, prefix, total, K2, E1, E2, T);
    sched_kernel<<<GB, 256, 0, stream>>>(nwv, prefix, N, sched);
    sample_kernel<<<SAMPLE_BLOCKS, 256, 0, stream>>>(geo, K1, T, img1, img2, sched, total, part);
    finalize_kernel<<<1, 256, 0, stream>>>(part, NPART, gnl, gzl, gcnt, N, NW, out);
}